// Round 1
// baseline (636.951 us; speedup 1.0000x reference)
//
#include <hip/hip_runtime.h>
#include <hip/hip_bf16.h>
#include <math.h>

// Problem constants (B=4, T=2048, C=1024, H=16, D=64)
#define SEQ   2048
#define NTOK  8192          // B*T
#define EMB   1024
#define QKVF  3072

typedef __bf16 bf16;
typedef __bf16 bf16x8 __attribute__((ext_vector_type(8)));
typedef __bf16 bf16x4 __attribute__((ext_vector_type(4)));
typedef float  f32x4  __attribute__((ext_vector_type(4)));

__device__ __forceinline__ void gload_lds16(const bf16* g, bf16* l) {
    __builtin_amdgcn_global_load_lds(
        (const __attribute__((address_space(1))) unsigned int*)g,
        (__attribute__((address_space(3))) unsigned int*)l,
        16, 0, 0);
}

// ---------------- fp32 -> bf16 conversion (vectorized x4) ----------------
__global__ __launch_bounds__(256) void cvt_f32_bf16(const float* __restrict__ in,
                                                    bf16* __restrict__ out, int n) {
    int i = (blockIdx.x * 256 + threadIdx.x) * 4;
    if (i >= n) return;
    float4 f = *reinterpret_cast<const float4*>(in + i);
    bf16x4 o;
    o[0] = (bf16)f.x; o[1] = (bf16)f.y; o[2] = (bf16)f.z; o[3] = (bf16)f.w;
    *reinterpret_cast<bf16x4*>(out + i) = o;
}

// ---------------- bt-GEMM: C[M,N] = A[M,K] * B[N,K]^T + bias ----------------
// 128x128 tile, BK=64, 256 threads = 4 waves in 2x2, each wave 64x64 (4x4 frags)
template <bool BF16OUT>
__global__ __launch_bounds__(256) void gemm_bt(const bf16* __restrict__ A,
                                               const bf16* __restrict__ Bm,
                                               const float* __restrict__ bias,
                                               void* __restrict__ out,
                                               int M, int N, int K) {
    __shared__ bf16 As[128 * 64];
    __shared__ bf16 Bs[128 * 64];

    const int tid  = threadIdx.x;
    const int lane = tid & 63;
    const int wv   = tid >> 6;
    const int wr   = wv >> 1, wc = wv & 1;
    const int lr   = lane & 15, hi = lane >> 4;
    const size_t brow = (size_t)blockIdx.y * 128;
    const size_t bcol = (size_t)blockIdx.x * 128;

    const f32x4 fzero = {0.f, 0.f, 0.f, 0.f};
    f32x4 acc[4][4];
#pragma unroll
    for (int m = 0; m < 4; ++m)
#pragma unroll
        for (int n = 0; n < 4; ++n) acc[m][n] = fzero;

    const int r8 = tid >> 3;      // staging row-within-chunk
    const int c8 = tid & 7;       // staging 16B-column

    for (int kt = 0; kt < K; kt += 64) {
#pragma unroll
        for (int i = 0; i < 4; ++i) {
            const int row = i * 32 + r8;
            const int lin = i * 256 + tid;
            gload_lds16(A  + (brow + row) * (size_t)K + kt + c8 * 8, &As[lin * 8]);
            gload_lds16(Bm + (bcol + row) * (size_t)K + kt + c8 * 8, &Bs[lin * 8]);
        }
        __syncthreads();   // compiler drains vmcnt before the barrier
#pragma unroll
        for (int kk = 0; kk < 2; ++kk) {
            bf16x8 af[4], bfr[4];
#pragma unroll
            for (int m = 0; m < 4; ++m)
                af[m] = *reinterpret_cast<const bf16x8*>(
                    &As[(wr * 64 + m * 16 + lr) * 64 + kk * 32 + hi * 8]);
#pragma unroll
            for (int n = 0; n < 4; ++n)
                bfr[n] = *reinterpret_cast<const bf16x8*>(
                    &Bs[(wc * 64 + n * 16 + lr) * 64 + kk * 32 + hi * 8]);
#pragma unroll
            for (int m = 0; m < 4; ++m)
#pragma unroll
                for (int n = 0; n < 4; ++n)
                    acc[m][n] = __builtin_amdgcn_mfma_f32_16x16x32_bf16(
                        af[m], bfr[n], acc[m][n], 0, 0, 0);
        }
        __syncthreads();   // protect As/Bs from next-iter staging
    }

#pragma unroll
    for (int m = 0; m < 4; ++m)
#pragma unroll
        for (int n = 0; n < 4; ++n)
#pragma unroll
            for (int r = 0; r < 4; ++r) {
                const size_t row = brow + wr * 64 + m * 16 + hi * 4 + r;
                const size_t col = bcol + wc * 64 + n * 16 + lr;
                const float v = acc[m][n][r] + bias[col];
                if (BF16OUT)
                    ((bf16*)out)[row * (size_t)N + col] = (bf16)v;
                else
                    ((float*)out)[row * (size_t)N + col] = v;
            }
}

// ---------------- causal flash attention ----------------
// qkv: [NTOK, 3072] bf16 (q|k|v each 1024, head-major inside).
// o:   [NTOK, 1024] bf16.
// grid: B * H * (T/64) blocks; 256 threads = 4 waves, wave w owns q rows [qbase+16w, +16)
__global__ __launch_bounds__(256) void attn_kernel(const bf16* __restrict__ qkv,
                                                   bf16* __restrict__ o) {
    const int bid = blockIdx.x;
    const int qt = bid & 31;          // T/64 = 32 q-tiles
    const int h  = (bid >> 5) & 15;
    const int b  = bid >> 9;
    const int qbase = qt * 64;

    const int tid  = threadIdx.x;
    const int wv   = tid >> 6;
    const int lane = tid & 63;
    const int lr   = lane & 15, hi = lane >> 4;

    __shared__ bf16 Ks[32 * 64];      // K tile, row-major [k][d]
    __shared__ bf16 Vt[64 * 32];      // V tile transposed [d][k]
    __shared__ bf16 Pl[4 * 16 * 32];  // per-wave P tiles [q][k]

    const size_t tokbase = (size_t)b * SEQ;

    // hoist Q fragments: A-operand rows = lr (wave-local q row), k = kk*32 + hi*8
    const bf16* qg = qkv + (tokbase + qbase + wv * 16 + lr) * (size_t)QKVF + h * 64;
    bf16x8 aq[2];
#pragma unroll
    for (int kk = 0; kk < 2; ++kk)
        aq[kk] = *reinterpret_cast<const bf16x8*>(qg + kk * 32 + hi * 8);

    const f32x4 fzero = {0.f, 0.f, 0.f, 0.f};
    f32x4 oacc[4];
#pragma unroll
    for (int n = 0; n < 4; ++n) oacc[n] = fzero;
    float m_r[4], l_r[4];
#pragma unroll
    for (int r = 0; r < 4; ++r) { m_r[r] = -__builtin_inff(); l_r[r] = 0.f; }

    const int nkv = qt * 2 + 2;       // KV tiles of 32 covering [0, qbase+64)

    for (int kt = 0; kt < nkv; ++kt) {
        __syncthreads();              // guard prev-iter LDS reads
        // stage K tile (linear, via global_load_lds): thread tid -> 16B chunk
        {
            const int row = tid >> 3, c8 = tid & 7;
            const bf16* kg = qkv + (tokbase + kt * 32 + row) * (size_t)QKVF
                             + EMB + h * 64 + c8 * 8;
            gload_lds16(kg, &Ks[tid * 8]);
        }
        // stage V transposed (register scatter)
        {
            const int k = tid >> 3, d0 = (tid & 7) * 8;
            const bf16* vg = qkv + (tokbase + kt * 32 + k) * (size_t)QKVF
                             + 2 * EMB + h * 64 + d0;
            bf16x8 v = *reinterpret_cast<const bf16x8*>(vg);
#pragma unroll
            for (int j = 0; j < 8; ++j) Vt[(d0 + j) * 32 + k] = v[j];
        }
        __syncthreads();

        // S = Q K^T for two 16-wide k subtiles
        f32x4 s[2];
        s[0] = fzero; s[1] = fzero;
#pragma unroll
        for (int st = 0; st < 2; ++st)
#pragma unroll
            for (int kk = 0; kk < 2; ++kk) {
                bf16x8 bk = *reinterpret_cast<const bf16x8*>(
                    &Ks[(st * 16 + lr) * 64 + kk * 32 + hi * 8]);
                s[st] = __builtin_amdgcn_mfma_f32_16x16x32_bf16(aq[kk], bk, s[st], 0, 0, 0);
            }

        // scale + causal mask; S lane layout: row q = hi*4+r, col k = st*16+lr
        const int qglob0 = qbase + wv * 16 + hi * 4;
#pragma unroll
        for (int st = 0; st < 2; ++st) {
            const int kglob = kt * 32 + st * 16 + lr;
#pragma unroll
            for (int r = 0; r < 4; ++r) {
                const float sv = s[st][r] * 0.125f;
                s[st][r] = (kglob <= qglob0 + r) ? sv : -__builtin_inff();
            }
        }

        // online softmax (row stats across 16 lanes of same hi-group)
        float tm[4];
#pragma unroll
        for (int r = 0; r < 4; ++r) tm[r] = fmaxf(s[0][r], s[1][r]);
#pragma unroll
        for (int mk = 1; mk <= 8; mk <<= 1)
#pragma unroll
            for (int r = 0; r < 4; ++r) tm[r] = fmaxf(tm[r], __shfl_xor(tm[r], mk));

        float mn[4], sc[4], p[2][4], ts[4];
#pragma unroll
        for (int r = 0; r < 4; ++r) {
            mn[r] = fmaxf(m_r[r], tm[r]);
            sc[r] = __expf(m_r[r] - mn[r]);
            ts[r] = 0.f;
        }
#pragma unroll
        for (int st = 0; st < 2; ++st)
#pragma unroll
            for (int r = 0; r < 4; ++r) {
                p[st][r] = __expf(s[st][r] - mn[r]);
                ts[r] += p[st][r];
            }
#pragma unroll
        for (int mk = 1; mk <= 8; mk <<= 1)
#pragma unroll
            for (int r = 0; r < 4; ++r) ts[r] += __shfl_xor(ts[r], mk);
#pragma unroll
        for (int r = 0; r < 4; ++r) {
            l_r[r] = l_r[r] * sc[r] + ts[r];
            m_r[r] = mn[r];
        }
#pragma unroll
        for (int n = 0; n < 4; ++n)
#pragma unroll
            for (int r = 0; r < 4; ++r) oacc[n][r] *= sc[r];

        // write P to LDS in [q][k] layout (wave-private region)
        bf16* pw = &Pl[wv * 512];
#pragma unroll
        for (int st = 0; st < 2; ++st)
#pragma unroll
            for (int r = 0; r < 4; ++r)
                pw[(hi * 4 + r) * 32 + st * 16 + lr] = (bf16)p[st][r];
        __syncthreads();

        // PV: A = P[16q x 32k], B = V[32k x d] read from Vt[d][k]
        bf16x8 ap = *reinterpret_cast<const bf16x8*>(&pw[lr * 32 + hi * 8]);
#pragma unroll
        for (int n = 0; n < 4; ++n) {
            bf16x8 bv = *reinterpret_cast<const bf16x8*>(&Vt[(n * 16 + lr) * 32 + hi * 8]);
            oacc[n] = __builtin_amdgcn_mfma_f32_16x16x32_bf16(ap, bv, oacc[n], 0, 0, 0);
        }
    }

    // epilogue: O / l, write bf16 [tok, h*64 + d]
    bf16* og = o + (tokbase + qbase + wv * 16) * (size_t)EMB + h * 64;
#pragma unroll
    for (int r = 0; r < 4; ++r) {
        const float inv = 1.f / l_r[r];
#pragma unroll
        for (int n = 0; n < 4; ++n)
            og[(hi * 4 + r) * (size_t)EMB + n * 16 + lr] = (bf16)(oacc[n][r] * inv);
    }
}

// ---------------- launcher ----------------
extern "C" void kernel_launch(void* const* d_in, const int* in_sizes, int n_in,
                              void* d_out, int out_size, void* d_ws, size_t ws_size,
                              hipStream_t stream) {
    const float* x     = (const float*)d_in[0];
    const float* qkv_w = (const float*)d_in[1];
    const float* qkv_b = (const float*)d_in[2];
    const float* out_w = (const float*)d_in[3];
    const float* out_b = (const float*)d_in[4];
    float* out = (float*)d_out;

    // workspace layout (needs ~88 MB)
    char* ws = (char*)d_ws;
    bf16* x_bf    = (bf16*)(ws);                                  // 16 MB
    bf16* qkvw_bf = (bf16*)(ws + 16777216);                       //  6 MB
    bf16* outw_bf = (bf16*)(ws + 23068672);                       //  2 MB
    bf16* qkv_bf  = (bf16*)(ws + 25165824);                       // 48 MB
    bf16* o_bf    = (bf16*)(ws + 75497472);                       // 16 MB

    cvt_f32_bf16<<<8192, 256, 0, stream>>>(x,     x_bf,    NTOK * EMB);
    cvt_f32_bf16<<<3072, 256, 0, stream>>>(qkv_w, qkvw_bf, QKVF * EMB);
    cvt_f32_bf16<<<1024, 256, 0, stream>>>(out_w, outw_bf, EMB * EMB);

    // QKV projection: [8192,1024] x [3072,1024]^T -> bf16 [8192,3072]
    gemm_bt<true><<<dim3(QKVF / 128, NTOK / 128), 256, 0, stream>>>(
        x_bf, qkvw_bf, qkv_b, qkv_bf, NTOK, QKVF, EMB);

    // causal attention -> bf16 [8192,1024]
    attn_kernel<<<4 * 16 * (SEQ / 64), 256, 0, stream>>>(qkv_bf, o_bf);

    // output projection: [8192,1024] x [1024,1024]^T -> f32 d_out
    gemm_bt<false><<<dim3(EMB / 128, NTOK / 128), 256, 0, stream>>>(
        o_bf, outw_bf, out_b, out, NTOK, EMB, EMB);
}

// Round 2
// 297.725 us; speedup vs baseline: 2.1394x; 2.1394x over previous
//
#include <hip/hip_runtime.h>
#include <hip/hip_bf16.h>
#include <math.h>

// Problem constants (B=4, T=2048, C=1024, H=16, D=64)
#define SEQ   2048
#define NTOK  8192          // B*T
#define EMB   1024
#define QKVF  3072

typedef __bf16 bf16;
typedef __bf16 bf16x8 __attribute__((ext_vector_type(8)));
typedef __bf16 bf16x4 __attribute__((ext_vector_type(4)));
typedef float  f32x4  __attribute__((ext_vector_type(4)));

__device__ __forceinline__ void gload_lds16(const bf16* g, bf16* l) {
    __builtin_amdgcn_global_load_lds(
        (const __attribute__((address_space(1))) unsigned int*)g,
        (__attribute__((address_space(3))) unsigned int*)l,
        16, 0, 0);
}

// ---------------- fp32 -> bf16 conversion (vectorized x4) ----------------
__global__ __launch_bounds__(256) void cvt_f32_bf16(const float* __restrict__ in,
                                                    bf16* __restrict__ out, int n) {
    int i = (blockIdx.x * 256 + threadIdx.x) * 4;
    if (i >= n) return;
    float4 f = *reinterpret_cast<const float4*>(in + i);
    bf16x4 o;
    o[0] = (bf16)f.x; o[1] = (bf16)f.y; o[2] = (bf16)f.z; o[3] = (bf16)f.w;
    *reinterpret_cast<bf16x4*>(out + i) = o;
}

// ---------------- bt-GEMM: C[M,N] = A[M,K] * B[N,K]^T + bias ----------------
// 128x128 tile, BK=64, 256 threads = 4 waves in 2x2, each wave 64x64 (4x4 frags)
// 1D grid with XCD-aware bijective swizzle (nwg % 8 == 0 for our shapes).
template <bool BF16OUT>
__global__ __launch_bounds__(256) void gemm_bt(const bf16* __restrict__ A,
                                               const bf16* __restrict__ Bm,
                                               const float* __restrict__ bias,
                                               void* __restrict__ out,
                                               int M, int N, int K) {
    __shared__ bf16 As[128 * 64];
    __shared__ bf16 Bs[128 * 64];

    const int nbx = N >> 7;
    const int nwg = nbx * (M >> 7);
    const int q8  = nwg >> 3;
    const int swz = (blockIdx.x & 7) * q8 + (blockIdx.x >> 3);
    const int bx  = swz % nbx;
    const int by  = swz / nbx;

    const int tid  = threadIdx.x;
    const int lane = tid & 63;
    const int wv   = tid >> 6;
    const int wr   = wv >> 1, wc = wv & 1;
    const int lr   = lane & 15, hi = lane >> 4;
    const size_t brow = (size_t)by * 128;
    const size_t bcol = (size_t)bx * 128;

    const f32x4 fzero = {0.f, 0.f, 0.f, 0.f};
    f32x4 acc[4][4];
#pragma unroll
    for (int m = 0; m < 4; ++m)
#pragma unroll
        for (int n = 0; n < 4; ++n) acc[m][n] = fzero;

    const int r8 = tid >> 3;      // staging row-within-chunk
    const int c8 = tid & 7;       // staging 16B-column

    for (int kt = 0; kt < K; kt += 64) {
#pragma unroll
        for (int i = 0; i < 4; ++i) {
            const int row = i * 32 + r8;
            const int lin = i * 256 + tid;
            gload_lds16(A  + (brow + row) * (size_t)K + kt + c8 * 8, &As[lin * 8]);
            gload_lds16(Bm + (bcol + row) * (size_t)K + kt + c8 * 8, &Bs[lin * 8]);
        }
        __syncthreads();
#pragma unroll
        for (int kk = 0; kk < 2; ++kk) {
            bf16x8 af[4], bfr[4];
#pragma unroll
            for (int m = 0; m < 4; ++m)
                af[m] = *reinterpret_cast<const bf16x8*>(
                    &As[(wr * 64 + m * 16 + lr) * 64 + kk * 32 + hi * 8]);
#pragma unroll
            for (int n = 0; n < 4; ++n)
                bfr[n] = *reinterpret_cast<const bf16x8*>(
                    &Bs[(wc * 64 + n * 16 + lr) * 64 + kk * 32 + hi * 8]);
#pragma unroll
            for (int m = 0; m < 4; ++m)
#pragma unroll
                for (int n = 0; n < 4; ++n)
                    acc[m][n] = __builtin_amdgcn_mfma_f32_16x16x32_bf16(
                        af[m], bfr[n], acc[m][n], 0, 0, 0);
        }
        __syncthreads();
    }

#pragma unroll
    for (int m = 0; m < 4; ++m)
#pragma unroll
        for (int n = 0; n < 4; ++n)
#pragma unroll
            for (int r = 0; r < 4; ++r) {
                const size_t row = brow + wr * 64 + m * 16 + hi * 4 + r;
                const size_t col = bcol + wc * 64 + n * 16 + lr;
                const float v = acc[m][n][r] + bias[col];
                if (BF16OUT)
                    ((bf16*)out)[row * (size_t)N + col] = (bf16)v;
                else
                    ((float*)out)[row * (size_t)N + col] = v;
            }
}

// ---------------- causal flash attention v2 ----------------
// q-tile 128 rows/block, 4 waves (32 q-rows each), KV tiles of 64.
// Swapped QK^T (mfma(K,Q)) -> lane-local softmax rows.
// grid: B*H*(T/128) = 1024 blocks; bid -> qt descending (long blocks first).
__global__ __launch_bounds__(256) void attn_kernel(const bf16* __restrict__ qkv,
                                                   bf16* __restrict__ o) {
    const int bid = blockIdx.x;
    const int qt  = 15 - (bid >> 6);     // 16 q-tiles; longest first
    const int bh  = bid & 63;
    const int h   = bh & 15;
    const int b   = bh >> 4;
    const int qbase = qt * 128;

    const int tid  = threadIdx.x;
    const int wv   = tid >> 6;
    const int lane = tid & 63;
    const int lr   = lane & 15, hi = lane >> 4;

    __shared__ bf16 Ks[64 * 64];          // K tile [k][d], XOR-swizzled rows
    __shared__ bf16 Vt[64 * 64];          // V^T tile [d][k], XOR-swizzled rows
    __shared__ bf16 Pl[4 * 32 * 64];      // per-wave P [q][k], XOR-swizzled rows

    char* Ksb = (char*)Ks;
    char* Vtb = (char*)Vt;
    char* Pb  = (char*)(Pl + wv * 2048);

    const size_t tokbase = (size_t)b * SEQ;

    // Hoist Q (B-operand): Q[q = qbase + wv*32 + qf*16 + lr][d = kk*32 + hi*8 ..]
    bf16x8 aq[2][2];
#pragma unroll
    for (int qf = 0; qf < 2; ++qf) {
        const bf16* qg = qkv + (tokbase + qbase + wv * 32 + qf * 16 + lr) * (size_t)QKVF
                         + h * 64;
#pragma unroll
        for (int kk = 0; kk < 2; ++kk)
            aq[qf][kk] = *reinterpret_cast<const bf16x8*>(qg + kk * 32 + hi * 8);
    }

    const f32x4 fzero = {0.f, 0.f, 0.f, 0.f};
    f32x4 oacc[2][4];
#pragma unroll
    for (int qf = 0; qf < 2; ++qf)
#pragma unroll
        for (int n = 0; n < 4; ++n) oacc[qf][n] = fzero;
    float m_r[2] = {-__builtin_inff(), -__builtin_inff()};
    float l_r[2] = {0.f, 0.f};

    const int nkv = qt * 2 + 2;           // KV tiles of 64 covering [0, qbase+128)
    const float SC = 0.125f * 1.44269504f; // 1/sqrt(64) * log2(e)

    // V staging mapping: thread -> (k = tid>>3 in 0..31 [and +32], chunk c = tid&7)
    const int vk0 = tid >> 3;
    const int vc  = tid & 7;

    for (int kt = 0; kt < nkv; ++kt) {
        const size_t kvrow = tokbase + (size_t)kt * 64;
        __syncthreads();   // previous iter's LDS reads complete

        // --- stage K [64][64] via global_load_lds, source pre-swizzled:
        // LDS slot (row kr, 16B-chunk bs) holds global chunk bs ^ (kr & 7)
#pragma unroll
        for (int j = 0; j < 2; ++j) {
            const int kr = wv * 16 + j * 8 + (lane >> 3);
            const int cg = (lane & 7) ^ ((lane >> 3) & 7);
            gload_lds16(qkv + (kvrow + kr) * (size_t)QKVF + EMB + h * 64 + cg * 8,
                        &Ks[(wv * 16 + j * 8) * 64 + lane * 8]);
        }

        // --- stage V transposed: Vt[d][k], byte = d*128 + ((2k) ^ ((d>>3)&7)<<4)
        {
            bf16x8 v0 = *reinterpret_cast<const bf16x8*>(
                qkv + (kvrow + vk0) * (size_t)QKVF + 2 * EMB + h * 64 + vc * 8);
            bf16x8 v1 = *reinterpret_cast<const bf16x8*>(
                qkv + (kvrow + vk0 + 32) * (size_t)QKVF + 2 * EMB + h * 64 + vc * 8);
#pragma unroll
            for (int jj = 0; jj < 8; ++jj) {
                const int d = vc * 8 + jj;              // d>>3 == vc
                char* row = Vtb + d * 128;
                *(bf16*)(row + ((vk0 * 2) ^ (vc << 4)))        = v0[jj];
                *(bf16*)(row + (((vk0 + 32) * 2) ^ (vc << 4))) = v1[jj];
            }
        }
        __syncthreads();

        // --- S^T = K Q^T : lane holds S[q = qf*16+lr][k = ktile*16 + hi*4 + r]
        f32x4 s[2][4];
#pragma unroll
        for (int qf = 0; qf < 2; ++qf)
#pragma unroll
            for (int ktile = 0; ktile < 4; ++ktile) s[qf][ktile] = fzero;
#pragma unroll
        for (int ktile = 0; ktile < 4; ++ktile)
#pragma unroll
            for (int kk = 0; kk < 2; ++kk) {
                const int kr = ktile * 16 + lr;
                bf16x8 ak = *reinterpret_cast<const bf16x8*>(
                    Ksb + kr * 128 + ((kk * 64 + hi * 16) ^ ((kr & 7) << 4)));
#pragma unroll
                for (int qf = 0; qf < 2; ++qf)
                    s[qf][ktile] = __builtin_amdgcn_mfma_f32_16x16x32_bf16(
                        ak, aq[qf][kk], s[qf][ktile], 0, 0, 0);
            }

        // --- scale + causal mask (pre-scaled into exp2 domain)
#pragma unroll
        for (int qf = 0; qf < 2; ++qf) {
            const int qglob = qbase + wv * 32 + qf * 16 + lr;
#pragma unroll
            for (int ktile = 0; ktile < 4; ++ktile) {
                const int kg0 = kt * 64 + ktile * 16 + hi * 4;
#pragma unroll
                for (int r = 0; r < 4; ++r) {
                    const float sv = s[qf][ktile][r] * SC;
                    s[qf][ktile][r] = (kg0 + r <= qglob) ? sv : -__builtin_inff();
                }
            }
        }

        // --- online softmax per qf (row = lane-local 16 values, reduce across hi)
#pragma unroll
        for (int qf = 0; qf < 2; ++qf) {
            float tm = s[qf][0][0];
#pragma unroll
            for (int ktile = 0; ktile < 4; ++ktile)
#pragma unroll
                for (int r = 0; r < 4; ++r) tm = fmaxf(tm, s[qf][ktile][r]);
            tm = fmaxf(tm, __shfl_xor(tm, 16));
            tm = fmaxf(tm, __shfl_xor(tm, 32));

            const float mn = fmaxf(m_r[qf], tm);
            const float sc = __builtin_amdgcn_exp2f(m_r[qf] - mn);
            m_r[qf] = mn;

            float ts = 0.f;
#pragma unroll
            for (int ktile = 0; ktile < 4; ++ktile)
#pragma unroll
                for (int r = 0; r < 4; ++r) {
                    const float p = __builtin_amdgcn_exp2f(s[qf][ktile][r] - mn);
                    s[qf][ktile][r] = p;
                    ts += p;
                }
            ts += __shfl_xor(ts, 16);
            ts += __shfl_xor(ts, 32);
            l_r[qf] = l_r[qf] * sc + ts;

            // broadcast rescale factors into C layout (row = hi*4+r)
            float scb[4];
#pragma unroll
            for (int r = 0; r < 4; ++r) scb[r] = __shfl(sc, hi * 4 + r);
#pragma unroll
            for (int n = 0; n < 4; ++n)
#pragma unroll
                for (int r = 0; r < 4; ++r) oacc[qf][n][r] *= scb[r];

            // write P (bf16) to wave-private LDS, swizzled rows
            const int q = qf * 16 + lr;
#pragma unroll
            for (int ktile = 0; ktile < 4; ++ktile) {
                bf16x4 p4;
#pragma unroll
                for (int r = 0; r < 4; ++r) p4[r] = (bf16)s[qf][ktile][r];
                *(bf16x4*)(Pb + q * 128 + ((ktile * 32 + hi * 8) ^ ((q & 7) << 4))) = p4;
            }
        }

        // --- PV: O += P V
#pragma unroll
        for (int kk = 0; kk < 2; ++kk) {
            bf16x8 ap[2];
#pragma unroll
            for (int qf = 0; qf < 2; ++qf) {
                const int q = qf * 16 + lr;
                ap[qf] = *reinterpret_cast<const bf16x8*>(
                    Pb + q * 128 + ((kk * 64 + hi * 16) ^ ((q & 7) << 4)));
            }
#pragma unroll
            for (int n = 0; n < 4; ++n) {
                const int d = n * 16 + lr;
                bf16x8 bv = *reinterpret_cast<const bf16x8*>(
                    Vtb + d * 128 + ((kk * 64 + hi * 16) ^ (((d >> 3) & 7) << 4)));
#pragma unroll
                for (int qf = 0; qf < 2; ++qf)
                    oacc[qf][n] = __builtin_amdgcn_mfma_f32_16x16x32_bf16(
                        ap[qf], bv, oacc[qf][n], 0, 0, 0);
            }
        }
    }

    // --- epilogue: normalize and store
#pragma unroll
    for (int qf = 0; qf < 2; ++qf) {
        const float linv = 1.f / l_r[qf];
        float li[4];
#pragma unroll
        for (int r = 0; r < 4; ++r) li[r] = __shfl(linv, hi * 4 + r);
        bf16* og = o + (tokbase + qbase + wv * 32 + qf * 16) * (size_t)EMB + h * 64;
#pragma unroll
        for (int n = 0; n < 4; ++n)
#pragma unroll
            for (int r = 0; r < 4; ++r)
                og[(hi * 4 + r) * (size_t)EMB + n * 16 + lr] =
                    (bf16)(oacc[qf][n][r] * li[r]);
    }
}

// ---------------- launcher ----------------
extern "C" void kernel_launch(void* const* d_in, const int* in_sizes, int n_in,
                              void* d_out, int out_size, void* d_ws, size_t ws_size,
                              hipStream_t stream) {
    const float* x     = (const float*)d_in[0];
    const float* qkv_w = (const float*)d_in[1];
    const float* qkv_b = (const float*)d_in[2];
    const float* out_w = (const float*)d_in[3];
    const float* out_b = (const float*)d_in[4];
    float* out = (float*)d_out;

    // workspace layout (needs ~88 MB)
    char* ws = (char*)d_ws;
    bf16* x_bf    = (bf16*)(ws);                                  // 16 MB
    bf16* qkvw_bf = (bf16*)(ws + 16777216);                       //  6 MB
    bf16* outw_bf = (bf16*)(ws + 23068672);                       //  2 MB
    bf16* qkv_bf  = (bf16*)(ws + 25165824);                       // 48 MB
    bf16* o_bf    = (bf16*)(ws + 75497472);                       // 16 MB

    cvt_f32_bf16<<<8192, 256, 0, stream>>>(x,     x_bf,    NTOK * EMB);
    cvt_f32_bf16<<<3072, 256, 0, stream>>>(qkv_w, qkvw_bf, QKVF * EMB);
    cvt_f32_bf16<<<1024, 256, 0, stream>>>(out_w, outw_bf, EMB * EMB);

    // QKV projection: [8192,1024] x [3072,1024]^T -> bf16 [8192,3072]
    gemm_bt<true><<<(QKVF / 128) * (NTOK / 128), 256, 0, stream>>>(
        x_bf, qkvw_bf, qkv_b, qkv_bf, NTOK, QKVF, EMB);

    // causal attention -> bf16 [8192,1024]
    attn_kernel<<<4 * 16 * (SEQ / 128), 256, 0, stream>>>(qkv_bf, o_bf);

    // output projection: [8192,1024] x [1024,1024]^T -> f32 d_out
    gemm_bt<false><<<(EMB / 128) * (NTOK / 128), 256, 0, stream>>>(
        o_bf, outw_bf, out_b, out, NTOK, EMB, EMB);
}